// Round 6
// baseline (6015.910 us; speedup 1.0000x reference)
//
#include <hip/hip_runtime.h>
#include <stdint.h>

#define T_SEQ   2048
#define NHEADS  16
#define HDIM    64
#define DMODEL  1024

// ================================================================ naive f32 GEMM-NT
// C[r,o] = sum_c A[r,c] * B[o,c];  A:[4096x1024], B:[1024x1024], C:[4096x1024]
// grid (64, 256) = (o-tiles, r-tiles), block 256 -> 16x16 output tile.
__global__ __launch_bounds__(256) void gemm_nt_f32(const float* __restrict__ A,
                                                   const float* __restrict__ B,
                                                   float* __restrict__ C) {
  __shared__ float As[16][68];   // +4 pad: 2-way max bank conflict
  __shared__ float Bs[16][68];
  const int tid = threadIdx.x;
  const int rl = tid >> 4, ol = tid & 15;
  const int r0 = blockIdx.y * 16, o0 = blockIdx.x * 16;
  float acc = 0.f;
  for (int k0 = 0; k0 < 1024; k0 += 64) {
    __syncthreads();
#pragma unroll
    for (int rep = 0; rep < 4; ++rep) {
      const int idx = rep * 256 + tid;      // 0..1023
      const int row = idx >> 6, col = idx & 63;
      As[row][col] = A[(size_t)(r0 + row) * 1024 + k0 + col];
      Bs[row][col] = B[(size_t)(o0 + row) * 1024 + k0 + col];
    }
    __syncthreads();
#pragma unroll 8
    for (int kk = 0; kk < 64; ++kk)
      acc += As[rl][kk] * Bs[ol][kk];
  }
  C[(size_t)(r0 + rl) * 1024 + o0 + ol] = acc;
}

// ================================================================ evolve + LayerNorm (f32)
// grid (T/128, B*H), block 64 (lane = d). Exact recurrence; warm-up 128 steps
// (0.7^128 ~ 2e-20 => exact in f32). eq separate buffer; ek in-place over k
// (strictly element-wise read-then-write by the owning thread; no cross-block k reads).
__global__ __launch_bounds__(64) void evolve_ln_f32(
    const float* __restrict__ q, float* k,
    const float* __restrict__ er_p, const float* __restrict__ md_p,
    const float* __restrict__ tw, const float* __restrict__ qgamma,
    const float* __restrict__ qbeta, const float* __restrict__ kgamma,
    const float* __restrict__ kbeta, float* __restrict__ eq) {
  const int lane = threadIdx.x;
  const int t0 = blockIdx.x * 128;
  const int bh = blockIdx.y;
  const int b = bh >> 4, h = bh & 15;
  const float sig_er = 1.f / (1.f + expf(-er_p[0]));
  const float smd    = 1.f / (1.f + expf(-md_p[0]));
  const float wv = tw[lane];
  const float gq = qgamma[lane], bq = qbeta[lane];
  const float gk = kgamma[lane], bk = kbeta[lane];
  const size_t base = ((size_t)b * T_SEQ) * DMODEL + h * HDIM + lane;

  float mem = 0.f;
  const int start = (t0 >= 128) ? (t0 - 128) : 0;
  for (int t = start; t < t0; ++t)
    mem = 0.7f * mem + 0.3f * q[base + (size_t)t * DMODEL];

  for (int t = t0; t < t0 + 128; ++t) {
    const float qv = q[base + (size_t)t * DMODEL];
    const float kv = k[base + (size_t)t * DMODEL];
    const float ts = sinf(sig_er * (float)(t + 1) * wv);
    const float xq = qv + ts + smd * mem;
    const float xk = kv + 0.5f * ts + 0.3f * smd * mem;
    float s1 = xq, s2 = xq * xq, s3 = xk, s4 = xk * xk;
#pragma unroll
    for (int off = 32; off > 0; off >>= 1) {
      s1 += __shfl_xor(s1, off);
      s2 += __shfl_xor(s2, off);
      s3 += __shfl_xor(s3, off);
      s4 += __shfl_xor(s4, off);
    }
    const float mq = s1 * (1.f / 64.f);
    const float vq = fmaxf(s2 * (1.f / 64.f) - mq * mq, 0.f);
    const float mk = s3 * (1.f / 64.f);
    const float vk = fmaxf(s4 * (1.f / 64.f) - mk * mk, 0.f);
    eq[base + (size_t)t * DMODEL] = (xq - mq) * rsqrtf(vq + 1e-5f) * gq + bq;
    k [base + (size_t)t * DMODEL] = (xk - mk) * rsqrtf(vk + 1e-5f) * gk + bk;
    mem = 0.7f * mem + 0.3f * qv;
  }
}

// ================================================================ naive flash attention (f32)
// One wave per (b,h,t) output row; lane = d. Online softmax, s-loop with
// 64-lane butterfly reduction for each score. Fully coalesced 256B row loads.
// grid 16384 blocks x 256 (4 waves/block); wid = b*32768 + h*2048 + t.
__global__ __launch_bounds__(256) void attn_naive_f32(
    const float* __restrict__ eq, const float* __restrict__ ek,
    const float* __restrict__ v, float* __restrict__ out) {
  const int wid = blockIdx.x * 4 + (threadIdx.x >> 6);
  const int lane = threadIdx.x & 63;
  const int t = wid & 2047;
  const int h = (wid >> 11) & 15;
  const int b = wid >> 15;
  const size_t base = ((size_t)b * T_SEQ) * DMODEL + h * HDIM + lane;

  const float qd = eq[base + (size_t)t * DMODEL];
  float m = -3.4e38f, l = 0.f, o = 0.f;
  for (int s = 0; s <= t; ++s) {
    float prod = qd * ek[base + (size_t)s * DMODEL];
#pragma unroll
    for (int off = 32; off > 0; off >>= 1) prod += __shfl_xor(prod, off);
    const float sc = prod * 0.125f;
    const float mn = fmaxf(m, sc);
    const float fac = __expf(m - mn);
    const float w = __expf(sc - mn);
    l = l * fac + w;
    o = o * fac + w * v[base + (size_t)s * DMODEL];
    m = mn;
  }
  out[base + (size_t)t * DMODEL] = o / l;
}

// ================================================================ launch
extern "C" void kernel_launch(void* const* d_in, const int* in_sizes, int n_in,
                              void* d_out, int out_size, void* d_ws, size_t ws_size,
                              hipStream_t stream) {
  const float* x  = (const float*)d_in[0];
  const float* Wq = (const float*)d_in[1];
  const float* Wk = (const float*)d_in[2];
  const float* Wv = (const float*)d_in[3];
  const float* Wo = (const float*)d_in[4];
  const float* er = (const float*)d_in[5];
  const float* md = (const float*)d_in[6];
  const float* tw = (const float*)d_in[7];
  const float* qg = (const float*)d_in[8];
  const float* qb = (const float*)d_in[9];
  const float* kg = (const float*)d_in[10];
  const float* kb = (const float*)d_in[11];

  const size_t NX = (size_t)2 * T_SEQ * DMODEL;   // 4194304 elements

  // Workspace: 4 x 16MB = 64MB, all f32. d_out untouched until final GEMM.
  float* qf  = (float*)d_ws;      // q; later reused as attention output
  float* kf  = qf + NX;           // k -> ek (in-place)
  float* vf  = kf + NX;           // v
  float* eqf = vf + NX;           // eq

  dim3 ggrid(DMODEL / 16, (2 * T_SEQ) / 16);   // (64, 256)
  gemm_nt_f32<<<ggrid, 256, 0, stream>>>(x, Wq, qf);
  gemm_nt_f32<<<ggrid, 256, 0, stream>>>(x, Wk, kf);
  gemm_nt_f32<<<ggrid, 256, 0, stream>>>(x, Wv, vf);

  evolve_ln_f32<<<dim3(T_SEQ / 128, 32), 64, 0, stream>>>(qf, kf, er, md, tw,
                                                          qg, qb, kg, kb, eqf);

  // q dead after evolve -> reuse qf as attention output
  attn_naive_f32<<<(2 * NHEADS * T_SEQ) / 4, 256, 0, stream>>>(eqf, kf, vf, qf);

  gemm_nt_f32<<<ggrid, 256, 0, stream>>>(qf, Wo, (float*)d_out);
}

// Round 8
// 4947.476 us; speedup vs baseline: 1.2160x; 1.2160x over previous
//
#include <hip/hip_runtime.h>
#include <stdint.h>

#define T_SEQ   2048
#define NHEADS  16
#define HDIM    64
#define DMODEL  1024

typedef __attribute__((ext_vector_type(8))) _Float16 half8_t;
typedef __attribute__((ext_vector_type(4))) float    float4_t;

__device__ __forceinline__ unsigned short f2h(float f) {
  _Float16 h = (_Float16)f;
  return __builtin_bit_cast(unsigned short, h);
}

// ================================================================ convert f32 -> f16
__global__ __launch_bounds__(256) void cvt_f32_f16(const float* __restrict__ s,
                                                   unsigned short* __restrict__ d, int n4) {
  int i = blockIdx.x * 256 + threadIdx.x;
  if (i >= n4) return;
  float4 v = ((const float4*)s)[i];
  ushort4 o;
  o.x = f2h(v.x); o.y = f2h(v.y); o.z = f2h(v.z); o.w = f2h(v.w);
  ((ushort4*)d)[i] = o;
}

// ================================================================ MFMA f16 GEMM-NT (convention probe)
// C[r,o] = sum_c A[r,c]*B[o,c]. A:[Mx1024] f16, B:[Nx1024] f16, C f32 [Mx1024].
// grid (N/128, M/128), block 256 = 4 waves (2x2), 64x64 per wave.
// Conventions under test (guide m89/m92): A-frag[row=lane&15][k=(lane>>4)*8+e],
// B-frag[col=lane&15][k], D[row=(lane>>4)*4+reg][col=lane&15].
__global__ __launch_bounds__(256) void gemm_nt_f16(const unsigned short* __restrict__ A,
                                                   const unsigned short* __restrict__ B,
                                                   float* __restrict__ C) {
  __shared__ alignas(16) unsigned short As[128 * 32];
  __shared__ alignas(16) unsigned short Bs[128 * 32];
  const int tid  = threadIdx.x;
  const int lane = tid & 63, w = tid >> 6;
  const int c = lane & 15, g = lane >> 4;
  const int wr = w >> 1, wc = w & 1;
  const int m0 = blockIdx.y * 128, n0 = blockIdx.x * 128;

  float4_t acc[4][4];
#pragma unroll
  for (int m = 0; m < 4; ++m)
#pragma unroll
    for (int n = 0; n < 4; ++n) acc[m][n] = (float4_t){0.f, 0.f, 0.f, 0.f};

  for (int k0 = 0; k0 < 1024; k0 += 32) {
    half8_t av[2], bv2[2];
#pragma unroll
    for (int r = 0; r < 2; ++r) {
      const int ci = r * 256 + tid;           // 0..511 chunks of 16B
      const int row = ci >> 2, kc = (ci & 3) * 8;
      av[r]  = *(const half8_t*)&A[(size_t)(m0 + row) * 1024 + k0 + kc];
      bv2[r] = *(const half8_t*)&B[(size_t)(n0 + row) * 1024 + k0 + kc];
    }
    __syncthreads();
#pragma unroll
    for (int r = 0; r < 2; ++r) {
      const int ci = r * 256 + tid;
      const int row = ci >> 2, kc = (ci & 3) * 8;
      *(half8_t*)&As[row * 32 + kc] = av[r];
      *(half8_t*)&Bs[row * 32 + kc] = bv2[r];
    }
    __syncthreads();
    half8_t af[4], bf[4];
#pragma unroll
    for (int m = 0; m < 4; ++m) af[m] = *(const half8_t*)&As[(wr * 64 + m * 16 + c) * 32 + g * 8];
#pragma unroll
    for (int n = 0; n < 4; ++n) bf[n] = *(const half8_t*)&Bs[(wc * 64 + n * 16 + c) * 32 + g * 8];
#pragma unroll
    for (int m = 0; m < 4; ++m)
#pragma unroll
      for (int n = 0; n < 4; ++n)
        acc[m][n] = __builtin_amdgcn_mfma_f32_16x16x32_f16(af[m], bf[n], acc[m][n], 0, 0, 0);
  }
#pragma unroll
  for (int m = 0; m < 4; ++m)
#pragma unroll
    for (int j = 0; j < 4; ++j) {
      const int row = m0 + wr * 64 + m * 16 + g * 4 + j;
#pragma unroll
      for (int n = 0; n < 4; ++n) {
        const int col = n0 + wc * 64 + n * 16 + c;
        C[(size_t)row * 1024 + col] = acc[m][n][j];
      }
    }
}

// ================================================================ evolve + LayerNorm (verified r6)
__global__ __launch_bounds__(64) void evolve_ln_f32(
    const float* __restrict__ q, float* k,
    const float* __restrict__ er_p, const float* __restrict__ md_p,
    const float* __restrict__ tw, const float* __restrict__ qgamma,
    const float* __restrict__ qbeta, const float* __restrict__ kgamma,
    const float* __restrict__ kbeta, float* __restrict__ eq) {
  const int lane = threadIdx.x;
  const int t0 = blockIdx.x * 128;
  const int bh = blockIdx.y;
  const int b = bh >> 4, h = bh & 15;
  const float sig_er = 1.f / (1.f + expf(-er_p[0]));
  const float smd    = 1.f / (1.f + expf(-md_p[0]));
  const float wv = tw[lane];
  const float gq = qgamma[lane], bq = qbeta[lane];
  const float gk = kgamma[lane], bk = kbeta[lane];
  const size_t base = ((size_t)b * T_SEQ) * DMODEL + h * HDIM + lane;

  float mem = 0.f;
  const int start = (t0 >= 128) ? (t0 - 128) : 0;
  for (int t = start; t < t0; ++t)
    mem = 0.7f * mem + 0.3f * q[base + (size_t)t * DMODEL];

  for (int t = t0; t < t0 + 128; ++t) {
    const float qv = q[base + (size_t)t * DMODEL];
    const float kv = k[base + (size_t)t * DMODEL];
    const float ts = sinf(sig_er * (float)(t + 1) * wv);
    const float xq = qv + ts + smd * mem;
    const float xk = kv + 0.5f * ts + 0.3f * smd * mem;
    float s1 = xq, s2 = xq * xq, s3 = xk, s4 = xk * xk;
#pragma unroll
    for (int off = 32; off > 0; off >>= 1) {
      s1 += __shfl_xor(s1, off);
      s2 += __shfl_xor(s2, off);
      s3 += __shfl_xor(s3, off);
      s4 += __shfl_xor(s4, off);
    }
    const float mq = s1 * (1.f / 64.f);
    const float vq = fmaxf(s2 * (1.f / 64.f) - mq * mq, 0.f);
    const float mk = s3 * (1.f / 64.f);
    const float vk = fmaxf(s4 * (1.f / 64.f) - mk * mk, 0.f);
    eq[base + (size_t)t * DMODEL] = (xq - mq) * rsqrtf(vq + 1e-5f) * gq + bq;
    k [base + (size_t)t * DMODEL] = (xk - mk) * rsqrtf(vk + 1e-5f) * gk + bk;
    mem = 0.7f * mem + 0.3f * qv;
  }
}

// ================================================================ naive flash attention (verified r6)
__global__ __launch_bounds__(256) void attn_naive_f32(
    const float* __restrict__ eq, const float* __restrict__ ek,
    const float* __restrict__ v, float* __restrict__ out) {
  const int wid = blockIdx.x * 4 + (threadIdx.x >> 6);
  const int lane = threadIdx.x & 63;
  const int t = wid & 2047;
  const int h = (wid >> 11) & 15;
  const int b = wid >> 15;
  const size_t base = ((size_t)b * T_SEQ) * DMODEL + h * HDIM + lane;

  const float qd = eq[base + (size_t)t * DMODEL];
  float m = -3.4e38f, l = 0.f, o = 0.f;
  for (int s = 0; s <= t; ++s) {
    float prod = qd * ek[base + (size_t)s * DMODEL];
#pragma unroll
    for (int off = 32; off > 0; off >>= 1) prod += __shfl_xor(prod, off);
    const float sc = prod * 0.125f;
    const float mn = fmaxf(m, sc);
    const float fac = __expf(m - mn);
    const float w = __expf(sc - mn);
    l = l * fac + w;
    o = o * fac + w * v[base + (size_t)s * DMODEL];
    m = mn;
  }
  out[base + (size_t)t * DMODEL] = o / l;
}

// ================================================================ launch
extern "C" void kernel_launch(void* const* d_in, const int* in_sizes, int n_in,
                              void* d_out, int out_size, void* d_ws, size_t ws_size,
                              hipStream_t stream) {
  const float* x  = (const float*)d_in[0];
  const float* Wq = (const float*)d_in[1];
  const float* Wk = (const float*)d_in[2];
  const float* Wv = (const float*)d_in[3];
  const float* Wo = (const float*)d_in[4];
  const float* er = (const float*)d_in[5];
  const float* md = (const float*)d_in[6];
  const float* tw = (const float*)d_in[7];
  const float* qg = (const float*)d_in[8];
  const float* qb = (const float*)d_in[9];
  const float* kg = (const float*)d_in[10];
  const float* kb = (const float*)d_in[11];

  const size_t NX = (size_t)2 * T_SEQ * DMODEL;   // 4194304
  const size_t NW = (size_t)DMODEL * DMODEL;      // 1048576

  // Workspace 64 MB (verified size). f32 tiers; f16 staging carved from dead regions.
  float* qf  = (float*)d_ws;      // [0,16) MB  q; attn out later
  float* kf  = qf + NX;           // [16,32)    k -> ek in-place
  float* vf  = kf + NX;           // [32,48)    v
  float* eqf = vf + NX;           // [48,64)    eq (written by evolve)

  // f16 staging inside [48,64) while eqf not yet written (dead until evolve):
  unsigned short* xh  = (unsigned short*)eqf;     // [48,56)
  unsigned short* wqh = xh + NX;                  // [56,58)
  unsigned short* wkh = wqh + NW;                 // [58,60)
  unsigned short* wvh = wkh + NW;                 // [60,62)
  // After attention, eqf dead again -> stage final-GEMM inputs there:
  unsigned short* aoh = (unsigned short*)eqf;     // [48,56) attn out f16
  unsigned short* woh = aoh + NX;                 // [56,58) Wo f16

  const int n4x = (int)(NX / 4), n4w = (int)(NW / 4);

  cvt_f32_f16<<<n4x / 256, 256, 0, stream>>>(x,  xh,  n4x);
  cvt_f32_f16<<<n4w / 256, 256, 0, stream>>>(Wq, wqh, n4w);
  cvt_f32_f16<<<n4w / 256, 256, 0, stream>>>(Wk, wkh, n4w);
  cvt_f32_f16<<<n4w / 256, 256, 0, stream>>>(Wv, wvh, n4w);

  dim3 ggrid(DMODEL / 128, (2 * T_SEQ) / 128);   // (8, 32)
  gemm_nt_f16<<<ggrid, 256, 0, stream>>>(xh, wqh, qf);
  gemm_nt_f16<<<ggrid, 256, 0, stream>>>(xh, wkh, kf);
  gemm_nt_f16<<<ggrid, 256, 0, stream>>>(xh, wvh, vf);

  // evolve writes eqf over [48,64) — xh/wqh/wkh/wvh dead by now
  evolve_ln_f32<<<dim3(T_SEQ / 128, 32), 64, 0, stream>>>(qf, kf, er, md, tw,
                                                          qg, qb, kg, kb, eqf);

  // q dead after evolve -> qf reused as attention output
  attn_naive_f32<<<(2 * NHEADS * T_SEQ) / 4, 256, 0, stream>>>(eqf, kf, vf, qf);

  // eqf dead after attention -> stage f16 inputs for final GEMM there
  cvt_f32_f16<<<n4x / 256, 256, 0, stream>>>(qf, aoh, n4x);
  cvt_f32_f16<<<n4w / 256, 256, 0, stream>>>(Wo, woh, n4w);

  gemm_nt_f16<<<ggrid, 256, 0, stream>>>(aoh, woh, (float*)d_out);
}